// Round 8
// baseline (134.424 us; speedup 1.0000x reference)
//
#include <hip/hip_runtime.h>
#include <hip/hip_bf16.h>

typedef __attribute__((ext_vector_type(8))) short  short8;
typedef __attribute__((ext_vector_type(8))) unsigned short ushort8;
typedef __attribute__((ext_vector_type(4))) unsigned short usv4;
typedef __attribute__((ext_vector_type(4))) float  f32x4;

#define D_DIM 1152
#define O_DIM 256
#define N_TOT 100352
#define XT_H 58
#define XT_ROW (58 * 128)

__device__ __forceinline__ unsigned short f2bf(float f) {
  __hip_bfloat16 h = __float2bfloat16(f);
  return __builtin_bit_cast(unsigned short, h);
}

#define GLOAD_LDS16(g, l)                                              \
  __builtin_amdgcn_global_load_lds(                                    \
      (const __attribute__((address_space(1))) void*)(g),              \
      (__attribute__((address_space(3))) void*)(l), 16, 0, 0)

// ---------------------------------------------------------------------------
// Kernel 1: Wt[o][dn] via LDS-tiled fp32 block-GEMM (proven R4)
// ---------------------------------------------------------------------------
__global__ __launch_bounds__(256) void wt_kernel(
    const float* __restrict__ S1s, const float* __restrict__ U1s,
    const float* __restrict__ U2s, const float* __restrict__ S2s,
    unsigned short* __restrict__ Wt) {
  __shared__ float A_lds[32][64];
  __shared__ float B_lds[32][64];

  const int bo = blockIdx.x & 3;
  const int bd = blockIdx.x >> 2;
  const int o0  = bo << 6;
  const int dn0 = bd << 6;
  const int rr  = dn0 >> 7;
  const int c0  = dn0 & 127;

  const int tid = threadIdx.x;
  const int ty = tid >> 4, tx = tid & 15;

  float acc[4][4] = {};

  for (int kc = 0; kc < 15; ++kc) {
#pragma unroll
    for (int e = 0; e < 8; ++e) {
      const int li = e * 256 + tid;
      const int kk = li >> 6;
      const int xx = li & 63;
      const int k  = kc * 32 + kk;
      float av, bv;
      if (k < 48) {
        av = U1s[k * O_DIM + o0 + xx];
        const int d_old = (c0 + xx) * 9 + rr;
        bv = S1s[(size_t)((k >> 3) * D_DIM + d_old) * 8 + (k & 7)];
      } else {
        const int kq = k - 48;
        av = S2s[(size_t)kq * O_DIM + o0 + xx];
        const int d_old = (c0 + xx) * 9 + rr;
        bv = U2s[(size_t)kq * D_DIM + d_old];
      }
      A_lds[kk][xx] = av;
      B_lds[kk][xx] = bv;
    }
    __syncthreads();
#pragma unroll
    for (int kk = 0; kk < 32; ++kk) {
      f32x4 a = *(const f32x4*)&A_lds[kk][ty << 2];
      f32x4 b = *(const f32x4*)&B_lds[kk][tx << 2];
#pragma unroll
      for (int i = 0; i < 4; ++i)
#pragma unroll
        for (int j = 0; j < 4; ++j)
          acc[i][j] += a[i] * b[j];
    }
    __syncthreads();
  }

#pragma unroll
  for (int i = 0; i < 4; ++i) {
    usv4 v;
#pragma unroll
    for (int j = 0; j < 4; ++j) v[j] = f2bf(acc[i][j] * (1.0f / 6.0f));
    *(usv4*)(Wt + (size_t)(o0 + (ty << 2) + i) * D_DIM + dn0 + (tx << 2)) = v;
  }
}

// ---------------------------------------------------------------------------
// Kernel 2: pad+transpose x[B,C,H,W] fp32 -> x_t[b][ih][iw][c] bf16 (proven R4)
// ---------------------------------------------------------------------------
__global__ __launch_bounds__(256) void pad_kernel(const float* __restrict__ x,
                                                  unsigned short* __restrict__ xt) {
  int blk = blockIdx.x;
  int b = blk / XT_H, ih = blk - b * XT_H;
  unsigned short* dst = xt + (size_t)blk * XT_ROW;
  int tid = threadIdx.x;

  if (ih == 0 || ih == XT_H - 1) {
    ushort8 z;
#pragma unroll
    for (int q = 0; q < 8; ++q) z[q] = 0;
    for (int i = tid; i < XT_ROW / 8; i += 256) ((ushort8*)dst)[i] = z;
    return;
  }

  __shared__ unsigned short lds[128 * 58];
  int h = ih - 1;
  const float* xb = x + (size_t)b * 128 * 3136 + (size_t)h * 56;
#pragma unroll 4
  for (int r = 0; r < 28; ++r) {
    int idx = r * 256 + tid;
    int c = idx / 56, w2 = idx - c * 56;
    lds[c * 58 + w2] = f2bf(xb[(size_t)c * 3136 + w2]);
  }
  __syncthreads();
#pragma unroll 4
  for (int r = 0; r < 29; ++r) {
    int idx = r * 256 + tid;
    int iw = idx >> 7, c = idx & 127;
    unsigned short v = 0;
    if (iw >= 1 && iw <= 56) v = lds[c * 58 + (iw - 1)];
    dst[idx] = v;
  }
}

// ---------------------------------------------------------------------------
// Kernel 3: implicit-im2col GEMM, 2-phase/K-tile pipelined schedule.
// BM=256 (all of O) x BN=256 n, BK=64, 8 waves (2Mx4N), wave-tile 128x64.
// Phase = K-slice of 32. LDS [2 buf][{A,B}][2 slices][256 rows][32 k] = 128KB.
// Stage stream (1 slice-pair = 4 gloads per phase) runs 4 phases ahead of
// consumption: (kt,p0) stages S1(kt+1), (kt,p1) stages S0(kt+2). Per-phase
// counted vmcnt(8) (2 slice-pairs in flight) before the trailing barrier
// guarantees the NEXT phase's slice is fully landed across all waves.
// Buffer-overwrite issues are always >=1 barrier after the last read of the
// region. 2-bit XOR group swizzle (g ^= row&3) balances LDS banks; global
// source is pre-swizzled, LDS dest stays linear (global_load_lds rule).
// ---------------------------------------------------------------------------
#define ABYTE(bf_, ks_) ((bf_) * 65536 + (ks_) * 16384)
#define BBYTE(bf_, ks_) ((bf_) * 65536 + 32768 + (ks_) * 16384)

__device__ __forceinline__ constexpr int KOF(int kt) {
  // xt element offset for K-tile kt: (kh*58+kw)*128 + (kt&1)*64
  int rr = kt >> 1;
  return ((rr / 3) * 58 + (rr % 3)) * 128 + (kt & 1) * 64;
}

#define STAGE(kt_, ks_, bf_) do {                                              \
  GLOAD_LDS16(pA0 + (kt_) * 64 + (ks_) * 32,                                   \
              smem + (ABYTE(bf_, ks_) >> 1) + stoff0);                         \
  GLOAD_LDS16(pA1 + (kt_) * 64 + (ks_) * 32,                                   \
              smem + (ABYTE(bf_, ks_) >> 1) + stoff1);                         \
  GLOAD_LDS16(pB0 + KOF(kt_) + (ks_) * 32,                                     \
              smem + (BBYTE(bf_, ks_) >> 1) + stoff0);                         \
  GLOAD_LDS16(pB1 + KOF(kt_) + (ks_) * 32,                                     \
              smem + (BBYTE(bf_, ks_) >> 1) + stoff1);                         \
} while (0)

__global__ __launch_bounds__(512, 2) void gemm_kernel(
    const unsigned short* __restrict__ Wt, const unsigned short* __restrict__ xt,
    const float* __restrict__ bias, float* __restrict__ out) {
  __shared__ __align__(1024) unsigned short smem[65536];  // 128 KiB

  // XCD swizzle (392 % 8 == 0): each XCD gets 49 consecutive n-tiles.
  const int bid   = blockIdx.x;
  const int ntile = (bid & 7) * 49 + (bid >> 3);
  const int n0    = ntile << 8;   // *256

  const int tid  = threadIdx.x;
  const int w    = tid >> 6;
  const int lane = tid & 63;
  const int wm   = w >> 2;       // 0..1  (o half)
  const int wn   = w & 3;        // 0..3  (n quarter)

  const int stoff0 = w << 9;               // (0*512 + w*64)*8 ushorts
  const int stoff1 = 4096 + (w << 9);      // (512 + w*64)*8

  // ---- staging source pointers (per-thread fixed; group pre-swizzled) ----
  const unsigned short *pA0, *pA1, *pB0, *pB1;
  {
    const int li0 = tid, li1 = 512 + tid;
    const int r0 = li0 >> 2, g0 = (li0 & 3) ^ (r0 & 3);
    const int r1 = li1 >> 2, g1 = (li1 & 3) ^ (r1 & 3);
    pA0 = Wt + (size_t)r0 * D_DIM + g0 * 8;
    pA1 = Wt + (size_t)r1 * D_DIM + g1 * 8;
    int n_g0 = n0 + r0;
    int b0 = n_g0 / 3136, s0 = n_g0 - b0 * 3136;
    int oh0 = s0 / 56, ow0 = s0 - oh0 * 56;
    pB0 = xt + (((size_t)b0 * XT_H + oh0) * XT_H + ow0) * 128 + g0 * 8;
    int n_g1 = n0 + r1;
    int b1 = n_g1 / 3136, s1 = n_g1 - b1 * 3136;
    int oh1 = s1 / 56, ow1 = s1 - oh1 * 56;
    pB1 = xt + (((size_t)b1 * XT_H + oh1) * XT_H + ow1) * 128 + g1 * 8;
  }

  f32x4 acc[8][4] = {};

  const int la15 = lane & 15;
  const int frq  = (((lane >> 4) ^ (lane & 3)) << 4);   // swizzled 16B group (bytes)

  // ---- prologue: S0(t0), S1(t0), S0(t1) ----
  STAGE(0, 0, 0);
  STAGE(0, 1, 0);
  STAGE(1, 0, 1);
  asm volatile("s_waitcnt vmcnt(8)" ::: "memory");   // S0(t0) landed
  __builtin_amdgcn_s_barrier();

#pragma unroll
  for (int kt = 0; kt < 18; ++kt) {
    const int bsel = kt & 1;
#pragma unroll
    for (int p = 0; p < 2; ++p) {
      const char* Abase = (const char*)smem + ABYTE(bsel, p);
      const char* Bbase = (const char*)smem + BBYTE(bsel, p);

      // ---- fragment reads for this K-slice ----
      short8 af[8], bfr[4];
#pragma unroll
      for (int mi = 0; mi < 8; ++mi)
        af[mi] = *(const short8*)(Abase + ((wm << 7) + (mi << 4) + la15) * 64 + frq);
#pragma unroll
      for (int ni = 0; ni < 4; ++ni)
        bfr[ni] = *(const short8*)(Bbase + ((wn << 6) + (ni << 4) + la15) * 64 + frq);

      // ---- stage (4 phases ahead of consumption) ----
      if (p == 0) {
        if (kt + 1 < 18) STAGE(kt + 1, 1, (kt + 1) & 1);
      } else {
        if (kt + 2 < 18) STAGE(kt + 2, 0, kt & 1);
      }
      __builtin_amdgcn_s_barrier();

      // ---- MFMA cluster ----
      __builtin_amdgcn_s_setprio(1);
#pragma unroll
      for (int mi = 0; mi < 8; ++mi)
#pragma unroll
        for (int ni = 0; ni < 4; ++ni)
          acc[mi][ni] = __builtin_amdgcn_mfma_f32_16x16x32_bf16(
              af[mi], bfr[ni], acc[mi][ni], 0, 0, 0);
      __builtin_amdgcn_s_setprio(0);

      // ---- counted wait protects the NEXT phase's reads ----
      if (kt < 16 || (kt == 16 && p == 0))
        asm volatile("s_waitcnt vmcnt(8)" ::: "memory");
      else if (kt == 16)
        asm volatile("s_waitcnt vmcnt(4)" ::: "memory");
      else if (kt == 17 && p == 0)
        asm volatile("s_waitcnt vmcnt(0)" ::: "memory");
      __builtin_amdgcn_s_barrier();
    }
  }

  // ---- epilogue: D row = o ((lane>>4)*4+reg), col = n (lane&15) ----
  const int lr = (lane >> 4) << 2;
#pragma unroll
  for (int ni = 0; ni < 4; ++ni) {
    const int ng = n0 + (wn << 6) + (ni << 4) + la15;
    const int b  = ng / 3136;
    const int s  = ng - b * 3136;
    float* op = out + (size_t)b * (O_DIM * 3136) + s;
#pragma unroll
    for (int mi = 0; mi < 8; ++mi) {
      const int og = (wm << 7) + (mi << 4) + lr;
#pragma unroll
      for (int r = 0; r < 4; ++r)
        op[(size_t)(og + r) * 3136] = acc[mi][ni][r] + 2.0f * bias[og + r];
    }
  }
}

// ---------------------------------------------------------------------------
extern "C" void kernel_launch(void* const* d_in, const int* in_sizes, int n_in,
                              void* d_out, int out_size, void* d_ws, size_t ws_size,
                              hipStream_t stream) {
  const float* x    = (const float*)d_in[0];
  const float* S1s  = (const float*)d_in[1];
  const float* U1s  = (const float*)d_in[2];
  const float* U2s  = (const float*)d_in[3];
  const float* S2s  = (const float*)d_in[4];
  const float* bias = (const float*)d_in[5];
  float* out = (float*)d_out;
  (void)ws_size;

  unsigned short* xt = (unsigned short*)d_ws;
  unsigned short* Wt = (unsigned short*)((char*)d_ws + (size_t)32 * XT_H * XT_ROW * 2);

  pad_kernel<<<dim3(32 * XT_H), dim3(256), 0, stream>>>(x, xt);
  wt_kernel<<<dim3(72), dim3(256), 0, stream>>>(S1s, U1s, U2s, S2s, Wt);
  gemm_kernel<<<dim3(392), dim3(512), 0, stream>>>(Wt, xt, bias, out);
}

// Round 9
// 126.698 us; speedup vs baseline: 1.0610x; 1.0610x over previous
//
#include <hip/hip_runtime.h>
#include <hip/hip_bf16.h>

typedef __attribute__((ext_vector_type(8))) short  short8;
typedef __attribute__((ext_vector_type(8))) unsigned short ushort8;
typedef __attribute__((ext_vector_type(4))) unsigned short usv4;
typedef __attribute__((ext_vector_type(4))) float  f32x4;

#define D_DIM 1152
#define O_DIM 256
#define N_TOT 100352
#define XT_H 58
#define XT_ROW (58 * 128)

__device__ __forceinline__ unsigned short f2bf(float f) {
  __hip_bfloat16 h = __float2bfloat16(f);
  return __builtin_bit_cast(unsigned short, h);
}

#define GLOAD_LDS16(g, l)                                              \
  __builtin_amdgcn_global_load_lds(                                    \
      (const __attribute__((address_space(1))) void*)(g),              \
      (__attribute__((address_space(3))) void*)(l), 16, 0, 0)

// ---------------------------------------------------------------------------
// Kernel 1: Wt[o][dn] via LDS-tiled fp32 block-GEMM (proven R4)
// ---------------------------------------------------------------------------
__global__ __launch_bounds__(256) void wt_kernel(
    const float* __restrict__ S1s, const float* __restrict__ U1s,
    const float* __restrict__ U2s, const float* __restrict__ S2s,
    unsigned short* __restrict__ Wt) {
  __shared__ float A_lds[32][64];
  __shared__ float B_lds[32][64];

  const int bo = blockIdx.x & 3;
  const int bd = blockIdx.x >> 2;
  const int o0  = bo << 6;
  const int dn0 = bd << 6;
  const int rr  = dn0 >> 7;
  const int c0  = dn0 & 127;

  const int tid = threadIdx.x;
  const int ty = tid >> 4, tx = tid & 15;

  float acc[4][4] = {};

  for (int kc = 0; kc < 15; ++kc) {
#pragma unroll
    for (int e = 0; e < 8; ++e) {
      const int li = e * 256 + tid;
      const int kk = li >> 6;
      const int xx = li & 63;
      const int k  = kc * 32 + kk;
      float av, bv;
      if (k < 48) {
        av = U1s[k * O_DIM + o0 + xx];
        const int d_old = (c0 + xx) * 9 + rr;
        bv = S1s[(size_t)((k >> 3) * D_DIM + d_old) * 8 + (k & 7)];
      } else {
        const int kq = k - 48;
        av = S2s[(size_t)kq * O_DIM + o0 + xx];
        const int d_old = (c0 + xx) * 9 + rr;
        bv = U2s[(size_t)kq * D_DIM + d_old];
      }
      A_lds[kk][xx] = av;
      B_lds[kk][xx] = bv;
    }
    __syncthreads();
#pragma unroll
    for (int kk = 0; kk < 32; ++kk) {
      f32x4 a = *(const f32x4*)&A_lds[kk][ty << 2];
      f32x4 b = *(const f32x4*)&B_lds[kk][tx << 2];
#pragma unroll
      for (int i = 0; i < 4; ++i)
#pragma unroll
        for (int j = 0; j < 4; ++j)
          acc[i][j] += a[i] * b[j];
    }
    __syncthreads();
  }

#pragma unroll
  for (int i = 0; i < 4; ++i) {
    usv4 v;
#pragma unroll
    for (int j = 0; j < 4; ++j) v[j] = f2bf(acc[i][j] * (1.0f / 6.0f));
    *(usv4*)(Wt + (size_t)(o0 + (ty << 2) + i) * D_DIM + dn0 + (tx << 2)) = v;
  }
}

// ---------------------------------------------------------------------------
// Kernel 2: pad+transpose x[B,C,H,W] fp32 -> x_t[b][ih][iw][c] bf16 (proven R4)
// ---------------------------------------------------------------------------
__global__ __launch_bounds__(256) void pad_kernel(const float* __restrict__ x,
                                                  unsigned short* __restrict__ xt) {
  int blk = blockIdx.x;
  int b = blk / XT_H, ih = blk - b * XT_H;
  unsigned short* dst = xt + (size_t)blk * XT_ROW;
  int tid = threadIdx.x;

  if (ih == 0 || ih == XT_H - 1) {
    ushort8 z;
#pragma unroll
    for (int q = 0; q < 8; ++q) z[q] = 0;
    for (int i = tid; i < XT_ROW / 8; i += 256) ((ushort8*)dst)[i] = z;
    return;
  }

  __shared__ unsigned short lds[128 * 58];
  int h = ih - 1;
  const float* xb = x + (size_t)b * 128 * 3136 + (size_t)h * 56;
#pragma unroll 4
  for (int r = 0; r < 28; ++r) {
    int idx = r * 256 + tid;
    int c = idx / 56, w2 = idx - c * 56;
    lds[c * 58 + w2] = f2bf(xb[(size_t)c * 3136 + w2]);
  }
  __syncthreads();
#pragma unroll 4
  for (int r = 0; r < 29; ++r) {
    int idx = r * 256 + tid;
    int iw = idx >> 7, c = idx & 127;
    unsigned short v = 0;
    if (iw >= 1 && iw <= 56) v = lds[c * 58 + (iw - 1)];
    dst[idx] = v;
  }
}

// ---------------------------------------------------------------------------
// Kernel 3: implicit-im2col GEMM, m201-style 4-phase/K-tile schedule.
// BM=256 (all O) x BN=256, BK=64, 8 waves (2Mx4N), wave-tile 128x64.
// LDS: 2 buffers x [A 256x64 | B 256x64] bf16, 128B rows = 128 KiB.
// R7-verified zero-conflict swizzle: 16B-granule kg = G ^ (row&7), matched by
// pre-swizzled global source (linear LDS dest, global_load_lds rule).
// Per K-tile: 4 phases {reads -> stage -> barrier -> lgkmcnt(0) ->
// setprio(1) 16xMFMA setprio(0) -> barrier}; all 8 staging gloads for kt+1
// issue in phases 1-2; single vmcnt(0) at phase-4 end (>=2 phases of slack).
// ---------------------------------------------------------------------------
__device__ __forceinline__ constexpr int KOF(int kt) {
  // xt element offset of K-tile kt: (kh*58+kw)*128 + (kt&1)*64
  int rr = kt >> 1;
  return ((rr / 3) * 58 + (rr % 3)) * 128 + (kt & 1) * 64;
}

// stage A rows [0..255] of K-tile kt_ into buffer bf_ (4 gloads)
#define ST_A(kt_, bf_) do {                                                    \
  GLOAD_LDS16(pA0 + (kt_) * 64,                  smem + (bf_) * 32768 + tid * 8);          \
  GLOAD_LDS16(pA0 + (kt_) * 64 +  64 * D_DIM,    smem + (bf_) * 32768 + 4096 + tid * 8);   \
  GLOAD_LDS16(pA0 + (kt_) * 64 + 128 * D_DIM,    smem + (bf_) * 32768 + 8192 + tid * 8);   \
  GLOAD_LDS16(pA0 + (kt_) * 64 + 192 * D_DIM,    smem + (bf_) * 32768 + 12288 + tid * 8);  \
} while (0)
// stage B rows [0..255] of K-tile kt_ into buffer bf_ (4 gloads)
#define ST_B(kt_, bf_) do {                                                    \
  GLOAD_LDS16(pB[0] + KOF(kt_), smem + (bf_) * 32768 + 16384 + tid * 8);       \
  GLOAD_LDS16(pB[1] + KOF(kt_), smem + (bf_) * 32768 + 20480 + tid * 8);       \
  GLOAD_LDS16(pB[2] + KOF(kt_), smem + (bf_) * 32768 + 24576 + tid * 8);       \
  GLOAD_LDS16(pB[3] + KOF(kt_), smem + (bf_) * 32768 + 28672 + tid * 8);       \
} while (0)

// fragment read: 128B rows, granule = (ks*4 + (lane>>4)) ^ (row&7)
#define AFRAG(bf_, row, ks)                                                    \
  (*(const short8*)((const char*)smem + (bf_) * 65536 + (row) * 128 +          \
      (((((ks) << 2) + (lane >> 4)) ^ ((row) & 7)) << 4)))
#define BFRAG(bf_, row, ks)                                                    \
  (*(const short8*)((const char*)smem + (bf_) * 65536 + 32768 + (row) * 128 +  \
      (((((ks) << 2) + (lane >> 4)) ^ ((row) & 7)) << 4)))

#define PHASE_BAR() do {                                                       \
  __builtin_amdgcn_s_barrier();                                                \
  asm volatile("s_waitcnt lgkmcnt(0)" ::: "memory");                           \
} while (0)

__global__ __launch_bounds__(512, 1) void gemm_kernel(
    const unsigned short* __restrict__ Wt, const unsigned short* __restrict__ xt,
    const float* __restrict__ bias, float* __restrict__ out) {
  __shared__ __align__(1024) unsigned short smem[65536];  // 128 KiB

  // XCD swizzle (392 % 8 == 0): each XCD gets 49 consecutive n-tiles.
  const int bid   = blockIdx.x;
  const int ntile = (bid & 7) * 49 + (bid >> 3);
  const int n0    = ntile << 8;

  const int tid  = threadIdx.x;
  const int w    = tid >> 6;
  const int lane = tid & 63;
  const int wm   = w >> 2;       // 0..1 (o half: 128 rows)
  const int wn   = w & 3;        // 0..3 (n quarter: 64 rows)
  const int la15 = lane & 15;

  // ---- staging sources: li = r*512+tid; row=li>>3; granule pre-swizzled.
  // row(r) = 64r + (tid>>3); (li&7)=(tid&7); row&7=(tid>>3)&7 (r-independent)
  const int srow = tid >> 3;
  const int sg   = (tid & 7) ^ (srow & 7);
  const unsigned short* pA0 = Wt + (size_t)srow * D_DIM + sg * 8;
  const unsigned short* pB[4];
#pragma unroll
  for (int r = 0; r < 4; ++r) {
    const int n_g = n0 + r * 64 + srow;
    const int b   = n_g / 3136;
    const int s   = n_g - b * 3136;
    const int oh  = s / 56, ow = s - oh * 56;
    pB[r] = xt + (((size_t)b * XT_H + oh) * XT_H + ow) * 128 + sg * 8;
  }

  f32x4 acc[8][4] = {};
  short8 afr[4], bfr[4];

  // ---- prologue: stage K-tile 0 into buf 0 ----
  ST_A(0, 0);
  ST_B(0, 0);
  asm volatile("s_waitcnt vmcnt(0)" ::: "memory");
  __builtin_amdgcn_s_barrier();

#pragma unroll
  for (int kt = 0; kt < 18; ++kt) {
    const int bf = kt & 1;
    const int nb = bf ^ 1;
    const bool more = (kt + 1) < 18;

    // ======== phase 1: A(mi0-3,ks0) + B(ks0); stage A(kt+1); MFMA q1 ========
#pragma unroll
    for (int mi = 0; mi < 4; ++mi)
      afr[mi] = AFRAG(bf, (wm << 7) + (mi << 4) + la15, 0);
#pragma unroll
    for (int ni = 0; ni < 4; ++ni)
      bfr[ni] = BFRAG(bf, (wn << 6) + (ni << 4) + la15, 0);
    if (more) ST_A(kt + 1, nb);
    PHASE_BAR();
    __builtin_amdgcn_s_setprio(1);
#pragma unroll
    for (int mi = 0; mi < 4; ++mi)
#pragma unroll
      for (int ni = 0; ni < 4; ++ni)
        acc[mi][ni] = __builtin_amdgcn_mfma_f32_16x16x32_bf16(
            afr[mi], bfr[ni], acc[mi][ni], 0, 0, 0);
    __builtin_amdgcn_s_setprio(0);
    __builtin_amdgcn_s_barrier();

    // ======== phase 2: A(mi4-7,ks0); stage B(kt+1); MFMA q2 (reuse B) ======
#pragma unroll
    for (int mi = 0; mi < 4; ++mi)
      afr[mi] = AFRAG(bf, (wm << 7) + ((mi + 4) << 4) + la15, 0);
    if (more) ST_B(kt + 1, nb);
    PHASE_BAR();
    __builtin_amdgcn_s_setprio(1);
#pragma unroll
    for (int mi = 0; mi < 4; ++mi)
#pragma unroll
      for (int ni = 0; ni < 4; ++ni)
        acc[4 + mi][ni] = __builtin_amdgcn_mfma_f32_16x16x32_bf16(
            afr[mi], bfr[ni], acc[4 + mi][ni], 0, 0, 0);
    __builtin_amdgcn_s_setprio(0);
    __builtin_amdgcn_s_barrier();

    // ======== phase 3: A(mi0-3,ks1) + B(ks1); MFMA q3 ======================
#pragma unroll
    for (int mi = 0; mi < 4; ++mi)
      afr[mi] = AFRAG(bf, (wm << 7) + (mi << 4) + la15, 1);
#pragma unroll
    for (int ni = 0; ni < 4; ++ni)
      bfr[ni] = BFRAG(bf, (wn << 6) + (ni << 4) + la15, 1);
    PHASE_BAR();
    __builtin_amdgcn_s_setprio(1);
#pragma unroll
    for (int mi = 0; mi < 4; ++mi)
#pragma unroll
      for (int ni = 0; ni < 4; ++ni)
        acc[mi][ni] = __builtin_amdgcn_mfma_f32_16x16x32_bf16(
            afr[mi], bfr[ni], acc[mi][ni], 0, 0, 0);
    __builtin_amdgcn_s_setprio(0);
    __builtin_amdgcn_s_barrier();

    // ======== phase 4: A(mi4-7,ks1); MFMA q4; drain kt+1 staging ===========
#pragma unroll
    for (int mi = 0; mi < 4; ++mi)
      afr[mi] = AFRAG(bf, (wm << 7) + ((mi + 4) << 4) + la15, 1);
    PHASE_BAR();
    __builtin_amdgcn_s_setprio(1);
#pragma unroll
    for (int mi = 0; mi < 4; ++mi)
#pragma unroll
      for (int ni = 0; ni < 4; ++ni)
        acc[4 + mi][ni] = __builtin_amdgcn_mfma_f32_16x16x32_bf16(
            afr[mi], bfr[ni], acc[4 + mi][ni], 0, 0, 0);
    __builtin_amdgcn_s_setprio(0);
    asm volatile("s_waitcnt vmcnt(0)" ::: "memory");  // kt+1 landed (2 phases old)
    __builtin_amdgcn_s_barrier();
  }

  // ---- epilogue: D row = o ((lane>>4)*4+reg), col = n (lane&15) ----
  const int lr = (lane >> 4) << 2;
#pragma unroll
  for (int ni = 0; ni < 4; ++ni) {
    const int ng = n0 + (wn << 6) + (ni << 4) + la15;
    const int b  = ng / 3136;
    const int s  = ng - b * 3136;
    float* op = out + (size_t)b * (O_DIM * 3136) + s;
#pragma unroll
    for (int mi = 0; mi < 8; ++mi) {
      const int og = (wm << 7) + (mi << 4) + lr;
#pragma unroll
      for (int r = 0; r < 4; ++r)
        op[(size_t)(og + r) * 3136] = acc[mi][ni][r] + 2.0f * bias[og + r];
    }
  }
}

// ---------------------------------------------------------------------------
extern "C" void kernel_launch(void* const* d_in, const int* in_sizes, int n_in,
                              void* d_out, int out_size, void* d_ws, size_t ws_size,
                              hipStream_t stream) {
  const float* x    = (const float*)d_in[0];
  const float* S1s  = (const float*)d_in[1];
  const float* U1s  = (const float*)d_in[2];
  const float* U2s  = (const float*)d_in[3];
  const float* S2s  = (const float*)d_in[4];
  const float* bias = (const float*)d_in[5];
  float* out = (float*)d_out;
  (void)ws_size;

  unsigned short* xt = (unsigned short*)d_ws;
  unsigned short* Wt = (unsigned short*)((char*)d_ws + (size_t)32 * XT_H * XT_ROW * 2);

  pad_kernel<<<dim3(32 * XT_H), dim3(256), 0, stream>>>(x, xt);
  wt_kernel<<<dim3(72), dim3(256), 0, stream>>>(S1s, U1s, U2s, S2s, Wt);
  gemm_kernel<<<dim3(392), dim3(512), 0, stream>>>(Wt, xt, bias, out);
}

// Round 10
// 122.210 us; speedup vs baseline: 1.0999x; 1.0367x over previous
//
#include <hip/hip_runtime.h>
#include <hip/hip_bf16.h>

typedef __attribute__((ext_vector_type(8))) short  short8;
typedef __attribute__((ext_vector_type(8))) unsigned short ushort8;
typedef __attribute__((ext_vector_type(4))) unsigned short usv4;
typedef __attribute__((ext_vector_type(4))) float  f32x4;

#define D_DIM 1152
#define O_DIM 256
#define N_TOT 100352
#define XT_H 58
#define XT_ROW (58 * 128)

__device__ __forceinline__ unsigned short f2bf(float f) {
  __hip_bfloat16 h = __float2bfloat16(f);
  return __builtin_bit_cast(unsigned short, h);
}

#define GLOAD_LDS16(g, l)                                              \
  __builtin_amdgcn_global_load_lds(                                    \
      (const __attribute__((address_space(1))) void*)(g),              \
      (__attribute__((address_space(3))) void*)(l), 16, 0, 0)

// ---------------------------------------------------------------------------
// Kernel 1: Wt[o][dn] via LDS-tiled fp32 block-GEMM (proven R4)
// ---------------------------------------------------------------------------
__global__ __launch_bounds__(256) void wt_kernel(
    const float* __restrict__ S1s, const float* __restrict__ U1s,
    const float* __restrict__ U2s, const float* __restrict__ S2s,
    unsigned short* __restrict__ Wt) {
  __shared__ float A_lds[32][64];
  __shared__ float B_lds[32][64];

  const int bo = blockIdx.x & 3;
  const int bd = blockIdx.x >> 2;
  const int o0  = bo << 6;
  const int dn0 = bd << 6;
  const int rr  = dn0 >> 7;
  const int c0  = dn0 & 127;

  const int tid = threadIdx.x;
  const int ty = tid >> 4, tx = tid & 15;

  float acc[4][4] = {};

  for (int kc = 0; kc < 15; ++kc) {
#pragma unroll
    for (int e = 0; e < 8; ++e) {
      const int li = e * 256 + tid;
      const int kk = li >> 6;
      const int xx = li & 63;
      const int k  = kc * 32 + kk;
      float av, bv;
      if (k < 48) {
        av = U1s[k * O_DIM + o0 + xx];
        const int d_old = (c0 + xx) * 9 + rr;
        bv = S1s[(size_t)((k >> 3) * D_DIM + d_old) * 8 + (k & 7)];
      } else {
        const int kq = k - 48;
        av = S2s[(size_t)kq * O_DIM + o0 + xx];
        const int d_old = (c0 + xx) * 9 + rr;
        bv = U2s[(size_t)kq * D_DIM + d_old];
      }
      A_lds[kk][xx] = av;
      B_lds[kk][xx] = bv;
    }
    __syncthreads();
#pragma unroll
    for (int kk = 0; kk < 32; ++kk) {
      f32x4 a = *(const f32x4*)&A_lds[kk][ty << 2];
      f32x4 b = *(const f32x4*)&B_lds[kk][tx << 2];
#pragma unroll
      for (int i = 0; i < 4; ++i)
#pragma unroll
        for (int j = 0; j < 4; ++j)
          acc[i][j] += a[i] * b[j];
    }
    __syncthreads();
  }

#pragma unroll
  for (int i = 0; i < 4; ++i) {
    usv4 v;
#pragma unroll
    for (int j = 0; j < 4; ++j) v[j] = f2bf(acc[i][j] * (1.0f / 6.0f));
    *(usv4*)(Wt + (size_t)(o0 + (ty << 2) + i) * D_DIM + dn0 + (tx << 2)) = v;
  }
}

// ---------------------------------------------------------------------------
// Kernel 2: pad+transpose x[B,C,H,W] fp32 -> x_t[b][ih][iw][c] bf16 (proven R4)
// ---------------------------------------------------------------------------
__global__ __launch_bounds__(256) void pad_kernel(const float* __restrict__ x,
                                                  unsigned short* __restrict__ xt) {
  int blk = blockIdx.x;
  int b = blk / XT_H, ih = blk - b * XT_H;
  unsigned short* dst = xt + (size_t)blk * XT_ROW;
  int tid = threadIdx.x;

  if (ih == 0 || ih == XT_H - 1) {
    ushort8 z;
#pragma unroll
    for (int q = 0; q < 8; ++q) z[q] = 0;
    for (int i = tid; i < XT_ROW / 8; i += 256) ((ushort8*)dst)[i] = z;
    return;
  }

  __shared__ unsigned short lds[128 * 58];
  int h = ih - 1;
  const float* xb = x + (size_t)b * 128 * 3136 + (size_t)h * 56;
#pragma unroll 4
  for (int r = 0; r < 28; ++r) {
    int idx = r * 256 + tid;
    int c = idx / 56, w2 = idx - c * 56;
    lds[c * 58 + w2] = f2bf(xb[(size_t)c * 3136 + w2]);
  }
  __syncthreads();
#pragma unroll 4
  for (int r = 0; r < 29; ++r) {
    int idx = r * 256 + tid;
    int iw = idx >> 7, c = idx & 127;
    unsigned short v = 0;
    if (iw >= 1 && iw <= 56) v = lds[c * 58 + (iw - 1)];
    dst[idx] = v;
  }
}

// ---------------------------------------------------------------------------
// Kernel 3: implicit-im2col GEMM with a true counted-vmcnt pipeline (T3+T4).
// BM=256(o) x BN=256(n), BK=64, 8 waves (2Mx4N), wave-tile 128x64.
// Pipeline unit = half-K-tile SLICE (K=32). LDS ring of 4 slots x
// [A 256x32 | B 256x32] bf16 = 32KB/slot = 128KB. Phase s: ds_read frags of
// slice s -> issue stage of slice s+3 -> s_waitcnt vmcnt(8) lgkmcnt(0)
// (slice s+1 landed; s+2,s+3 stay in flight -- NEVER drains to 0 until the
// last 2 phases) -> s_barrier -> sched_barrier -> setprio(1) 32 MFMA.
// One barrier per phase. Race ledger: (a) own ds_reads drained (lgkmcnt(0))
// before barrier, so slot (s+3)&3 == (s-1)&3 restage next phase is safe;
// (b) counted vmcnt before barrier makes every wave's slice-s+1 loads
// visible to all waves after it.
// Swizzle (64B rows, 4 granules of 16B): bank = ((row&1)<<4)|(g<<2)|..,
// so granule' = g ^ ((row>>1)&3) spreads 16 row-consecutive lanes over all
// 8 bank-quads (2 lanes/bank = free). Applied on BOTH sides: pre-swizzled
// global source (linear LDS dest, global_load_lds rule) + swizzled ds_read.
// ---------------------------------------------------------------------------
__device__ __forceinline__ constexpr int KOF(int kt) {
  // xt element offset of K-tile kt: (kh*58+kw)*128 + (kt&1)*64
  int rr = kt >> 1;
  return ((rr / 3) * 58 + (rr % 3)) * 128 + (kt & 1) * 64;
}

// stage slice s_ (4 gloads: A rows 0-127, A rows 128-255, B 0-127, B 128-255)
#define STAGE_S(s_) do {                                                       \
  GLOAD_LDS16(pA0 + (s_) * 32, smem + ((s_) & 3) * 16384 + (tid << 3));        \
  GLOAD_LDS16(pA1 + (s_) * 32, smem + ((s_) & 3) * 16384 + 4096 + (tid << 3)); \
  GLOAD_LDS16(pB0 + KOF((s_) >> 1) + ((s_) & 1) * 32,                          \
              smem + ((s_) & 3) * 16384 + 8192 + (tid << 3));                  \
  GLOAD_LDS16(pB1 + KOF((s_) >> 1) + ((s_) & 1) * 32,                          \
              smem + ((s_) & 3) * 16384 + 12288 + (tid << 3));                 \
} while (0)

// fragment reads: 64B rows; granule = (lane>>4) ^ ((row>>1)&3)
#define AFRAG(q_, row_)                                                        \
  (*(const short8*)((const char*)smem + (q_) * 32768 + (row_) * 64 +          \
      ((((lane >> 4) ^ (((row_) >> 1) & 3)) << 4))))
#define BFRAG(q_, row_)                                                        \
  (*(const short8*)((const char*)smem + (q_) * 32768 + 16384 + (row_) * 64 +  \
      ((((lane >> 4) ^ (((row_) >> 1) & 3)) << 4))))

__global__ __launch_bounds__(512, 1) void gemm_kernel(
    const unsigned short* __restrict__ Wt, const unsigned short* __restrict__ xt,
    const float* __restrict__ bias, float* __restrict__ out) {
  __shared__ __align__(1024) unsigned short smem[65536];  // 128 KiB

  // XCD swizzle (392 % 8 == 0): each XCD gets 49 consecutive n-tiles.
  const int bid   = blockIdx.x;
  const int ntile = (bid & 7) * 49 + (bid >> 3);
  const int n0    = ntile << 8;

  const int tid  = threadIdx.x;
  const int lane = tid & 63;
  const int w    = tid >> 6;
  const int wm   = w >> 2;       // 0..1 (o half: 128 rows)
  const int wn   = w & 3;        // 0..3 (n quarter: 64 rows)
  const int la15 = lane & 15;

  // ---- staging sources. Thread tid, gload i: LDS row = i*128 + (tid>>2),
  // stored granule = tid&3; must fetch logical granule g^((row>>1)&3).
  // (row>>1)&3 == (tid>>3)&3 for both i (128>>1 == 64 == 0 mod 4).
  const int srow = tid >> 2;
  const int glog = (tid & 3) ^ ((tid >> 3) & 3);
  const unsigned short* pA0 = Wt + (size_t)srow * D_DIM + glog * 8;
  const unsigned short* pA1 = Wt + (size_t)(128 + srow) * D_DIM + glog * 8;
  const unsigned short *pB0, *pB1;
  {
    int n_g = n0 + srow;
    int b = n_g / 3136, s = n_g - b * 3136;
    int oh = s / 56, ow = s - oh * 56;
    pB0 = xt + (((size_t)b * XT_H + oh) * XT_H + ow) * 128 + glog * 8;
    n_g = n0 + 128 + srow;
    b = n_g / 3136; s = n_g - b * 3136;
    oh = s / 56; ow = s - oh * 56;
    pB1 = xt + (((size_t)b * XT_H + oh) * XT_H + ow) * 128 + glog * 8;
  }

  f32x4 acc[8][4] = {};

  // ---- prologue: stage slices 0,1,2; wait slice 0 ----
  STAGE_S(0);
  STAGE_S(1);
  STAGE_S(2);
  asm volatile("s_waitcnt vmcnt(8)" ::: "memory");
  __builtin_amdgcn_s_barrier();

#pragma unroll
  for (int s = 0; s < 36; ++s) {
    const int q = s & 3;

    // ---- fragment reads for slice s ----
    short8 afr[8], bfr[4];
#pragma unroll
    for (int mi = 0; mi < 8; ++mi)
      afr[mi] = AFRAG(q, (wm << 7) + (mi << 4) + la15);
#pragma unroll
    for (int ni = 0; ni < 4; ++ni)
      bfr[ni] = BFRAG(q, (wn << 6) + (ni << 4) + la15);

    // ---- stage slice s+3 into slot (s-1)&3 (freed by last phase's barrier)
    if (s + 3 < 36) STAGE_S(s + 3);

    // ---- counted wait: slice s+1 landed; own ds_reads drained ----
    if (s <= 32)      asm volatile("s_waitcnt vmcnt(8) lgkmcnt(0)" ::: "memory");
    else if (s == 33) asm volatile("s_waitcnt vmcnt(4) lgkmcnt(0)" ::: "memory");
    else              asm volatile("s_waitcnt vmcnt(0) lgkmcnt(0)" ::: "memory");
    if (s < 35) __builtin_amdgcn_s_barrier();
    __builtin_amdgcn_sched_barrier(0);

    // ---- MFMA cluster: 32 per wave ----
    __builtin_amdgcn_s_setprio(1);
#pragma unroll
    for (int mi = 0; mi < 8; ++mi)
#pragma unroll
      for (int ni = 0; ni < 4; ++ni)
        acc[mi][ni] = __builtin_amdgcn_mfma_f32_16x16x32_bf16(
            afr[mi], bfr[ni], acc[mi][ni], 0, 0, 0);
    __builtin_amdgcn_s_setprio(0);
  }

  // ---- epilogue: D row = o ((lane>>4)*4+reg), col = n (lane&15) ----
  const int lr = (lane >> 4) << 2;
#pragma unroll
  for (int ni = 0; ni < 4; ++ni) {
    const int ng = n0 + (wn << 6) + (ni << 4) + la15;
    const int b  = ng / 3136;
    const int s  = ng - b * 3136;
    float* op = out + (size_t)b * (O_DIM * 3136) + s;
#pragma unroll
    for (int mi = 0; mi < 8; ++mi) {
      const int og = (wm << 7) + (mi << 4) + lr;
#pragma unroll
      for (int r = 0; r < 4; ++r)
        op[(size_t)(og + r) * 3136] = acc[mi][ni][r] + 2.0f * bias[og + r];
    }
  }
}

// ---------------------------------------------------------------------------
extern "C" void kernel_launch(void* const* d_in, const int* in_sizes, int n_in,
                              void* d_out, int out_size, void* d_ws, size_t ws_size,
                              hipStream_t stream) {
  const float* x    = (const float*)d_in[0];
  const float* S1s  = (const float*)d_in[1];
  const float* U1s  = (const float*)d_in[2];
  const float* U2s  = (const float*)d_in[3];
  const float* S2s  = (const float*)d_in[4];
  const float* bias = (const float*)d_in[5];
  float* out = (float*)d_out;
  (void)ws_size;

  unsigned short* xt = (unsigned short*)d_ws;
  unsigned short* Wt = (unsigned short*)((char*)d_ws + (size_t)32 * XT_H * XT_ROW * 2);

  pad_kernel<<<dim3(32 * XT_H), dim3(256), 0, stream>>>(x, xt);
  wt_kernel<<<dim3(72), dim3(256), 0, stream>>>(S1s, U1s, U2s, S2s, Wt);
  gemm_kernel<<<dim3(392), dim3(512), 0, stream>>>(Wt, xt, bias, out);
}